// Round 1
// baseline (453.043 us; speedup 1.0000x reference)
//
#include <hip/hip_runtime.h>

typedef unsigned short ushort_t;
typedef __attribute__((ext_vector_type(8))) short short8;   // 8 bf16 (4 VGPRs)
typedef __attribute__((ext_vector_type(4))) float f32x4;

#define S_  2048
#define Dm  2048
#define NH  16
#define NKV 4
#define HD_ 128
#define SCALE_ 0.08838834764831845f

__device__ __forceinline__ ushort_t f2bf(float f) {
  union { float f; unsigned u; } v; v.f = f;
  unsigned u = v.u;
  return (ushort_t)((u + 0x7FFFu + ((u >> 16) & 1u)) >> 16);   // RNE
}
__device__ __forceinline__ float bf2f(ushort_t h) {
  union { unsigned u; float f; } v; v.u = ((unsigned)h) << 16;
  return v.f;
}
__device__ __forceinline__ void gl_lds16(const void* g, void* l) {
  __builtin_amdgcn_global_load_lds((const __attribute__((address_space(1))) void*)g,
                                   (__attribute__((address_space(3))) void*)l, 16, 0, 0);
}

// ---------------- converters ----------------
__global__ void conv_f32_bf16(const float* __restrict__ src, ushort_t* __restrict__ dst) {
  int i = blockIdx.x * 256 + threadIdx.x;          // exact grid, no bounds check
  float4 v = ((const float4*)src)[i];
  union { ushort_t u[4]; uint2 v2; } o;
  o.u[0] = f2bf(v.x); o.u[1] = f2bf(v.y); o.u[2] = f2bf(v.z); o.u[3] = f2bf(v.w);
  *(uint2*)&dst[(size_t)i * 4] = o.v2;
}

// dst[n][k] = src[k][n], dst leading dim 2048, src is [2048][N] fp32
__global__ void transpose_conv(const float* __restrict__ src, int N, ushort_t* __restrict__ dst) {
  __shared__ float tile[32][33];
  int n0 = blockIdx.x * 32, k0 = blockIdx.y * 32;
  int c = threadIdx.x & 31, r = threadIdx.x >> 5;   // r: 0..7
#pragma unroll
  for (int i = 0; i < 32; i += 8)
    tile[r + i][c] = src[(size_t)(k0 + r + i) * N + n0 + c];
  __syncthreads();
#pragma unroll
  for (int i = 0; i < 32; i += 8)
    dst[(size_t)(n0 + r + i) * 2048 + k0 + c] = f2bf(tile[c][r + i]);
}

// vt[(b*4+kvh)*128 + d][s] = V[b*2048+s][d]  (V = qkv cols 2560..3071)
__global__ void transpose_v(const ushort_t* __restrict__ qkv, ushort_t* __restrict__ vt) {
  __shared__ ushort_t tile[32][33];
  int b = blockIdx.z >> 2, kvh = blockIdx.z & 3;
  int s0 = blockIdx.x * 32, d0 = blockIdx.y * 32;
  int c = threadIdx.x & 31, r = threadIdx.x >> 5;
#pragma unroll
  for (int i = 0; i < 32; i += 8)
    tile[r + i][c] = qkv[(size_t)(b * S_ + s0 + r + i) * 3072 + 2560 + kvh * HD_ + d0 + c];
  __syncthreads();
#pragma unroll
  for (int i = 0; i < 32; i += 8)
    vt[(size_t)(blockIdx.z * 128 + d0 + r + i) * S_ + s0 + c] = tile[c][r + i];
}

// ---------------- RoPE in place on Q,K ----------------
__global__ void rope_k(ushort_t* __restrict__ qkv, const float* __restrict__ cosT,
                       const float* __restrict__ sinT) {
  int idx = blockIdx.x * 256 + threadIdx.x;   // 4096*20*64 exact
  int d = idx & 63;
  int rest = idx >> 6;
  int hh = rest % 20;
  int row = rest / 20;
  int b = row >> 11, s = row & 2047;
  int col0 = (hh < 16) ? hh * 128 : 2048 + (hh - 16) * 128;
  float c  = cosT[(size_t)(b * S_ + s) * HD_ + d];   // cos[d] == cos[d+64]
  float sn = sinT[(size_t)(b * S_ + s) * HD_ + d];
  ushort_t* p = qkv + (size_t)row * 3072 + col0 + d;
  float v0 = bf2f(p[0]), v1 = bf2f(p[64]);
  p[0]  = f2bf(v0 * c - v1 * sn);
  p[64] = f2bf(v1 * c + v0 * sn);
}

// ---------------- GEMM: C[M][N] = A[M][K] @ Bt[N][K]^T, bf16 in, m97 structure ----------------
// MODE 0: bf16 out + packed qkv bias.  MODE 1: fp32 out, no bias.
template <int MODE>
__global__ __launch_bounds__(256, 2) void gemm_bt_k(
    const ushort_t* __restrict__ A, const ushort_t* __restrict__ Bt, void* __restrict__ C,
    int N, int K, const float* __restrict__ bq, const float* __restrict__ bk2,
    const float* __restrict__ bv) {
  __shared__ ushort_t lA[128 * 32];   // 8KB, source-pre-swizzled: slot ^= (row>>1)&3
  __shared__ ushort_t lB[128 * 32];
  const int n0 = blockIdx.x * 128, m0 = blockIdx.y * 128;
  const int t = threadIdx.x;
  const int w = t >> 6, l = t & 63, lr = l & 15, lg = l >> 4;
  const int wr = w >> 1, wc = w & 1;
  const int srow = t >> 2, ssl = t & 3;

  f32x4 acc[4][4];
#pragma unroll
  for (int i = 0; i < 4; i++)
#pragma unroll
    for (int j = 0; j < 4; j++) acc[i][j] = (f32x4){0.f, 0.f, 0.f, 0.f};

  for (int kt = 0; kt < K; kt += 32) {
    {
      int r0 = srow, r1 = srow + 64;
      gl_lds16(A + (size_t)(m0 + r0) * K + kt + ((ssl ^ ((r0 >> 1) & 3)) << 3), &lA[w * 512]);
      gl_lds16(A + (size_t)(m0 + r1) * K + kt + ((ssl ^ ((r1 >> 1) & 3)) << 3), &lA[2048 + w * 512]);
      gl_lds16(Bt + (size_t)(n0 + r0) * K + kt + ((ssl ^ ((r0 >> 1) & 3)) << 3), &lB[w * 512]);
      gl_lds16(Bt + (size_t)(n0 + r1) * K + kt + ((ssl ^ ((r1 >> 1) & 3)) << 3), &lB[2048 + w * 512]);
    }
    __syncthreads();
    short8 af[4], bfr[4];
#pragma unroll
    for (int mi = 0; mi < 4; mi++) {
      int row = wr * 64 + mi * 16 + lr;
      af[mi] = *(const short8*)((const char*)lA + row * 64 + ((lg ^ ((row >> 1) & 3)) << 4));
    }
#pragma unroll
    for (int ni = 0; ni < 4; ni++) {
      int row = wc * 64 + ni * 16 + lr;
      bfr[ni] = *(const short8*)((const char*)lB + row * 64 + ((lg ^ ((row >> 1) & 3)) << 4));
    }
#pragma unroll
    for (int mi = 0; mi < 4; mi++)
#pragma unroll
      for (int ni = 0; ni < 4; ni++)
        acc[mi][ni] = __builtin_amdgcn_mfma_f32_16x16x32_bf16(af[mi], bfr[ni], acc[mi][ni], 0, 0, 0);
    __syncthreads();
  }
#pragma unroll
  for (int mi = 0; mi < 4; mi++)
#pragma unroll
    for (int ni = 0; ni < 4; ni++)
#pragma unroll
      for (int r = 0; r < 4; r++) {
        int row = m0 + wr * 64 + mi * 16 + lg * 4 + r;   // C/D: col=lane&15, row=(lane>>4)*4+reg
        int col = n0 + wc * 64 + ni * 16 + lr;
        float v = acc[mi][ni][r];
        if (MODE == 0) {
          float bias = (col < 2048) ? bq[col] : (col < 2560) ? bk2[col - 2048] : bv[col - 2560];
          ((ushort_t*)C)[(size_t)row * N + col] = f2bf(v + bias);
        } else {
          ((float*)C)[(size_t)row * N + col] = v;
        }
      }
}

// ---------------- fused causal GQA attention, 2-pass flash, writes P + O ----------------
__global__ __launch_bounds__(256, 2) void attn_k(
    const ushort_t* __restrict__ qkv, const ushort_t* __restrict__ vt,
    float* __restrict__ wout, ushort_t* __restrict__ attnO) {
  __shared__ ushort_t lK[64 * 128];     // [k][d], 16 slots/row, slot ^= row&15
  __shared__ ushort_t lV[128 * 64];     // [d][k], 8 slots/row,  slot ^= row&7
  __shared__ ushort_t lP[4][32 * 64];   // per-wave P, 8 slots/row, slot ^= row&7
  const int qt = blockIdx.x, h = blockIdx.y, b = blockIdx.z;
  const int kvh = h >> 2;
  const int t = threadIdx.x, w = t >> 6, l = t & 63, lr = l & 15, lg = l >> 4;
  const int q0 = qt * 128;
  const int qw = q0 + w * 32;
  const int nkt = (qt + 1) * 2;   // 64-wide k-tiles covering the causal range

  // Q fragments in registers (A-frag: row=lane&15, k=(lane>>4)*8+i)
  short8 qf[2][4];
#pragma unroll
  for (int mi = 0; mi < 2; mi++)
#pragma unroll
    for (int kc = 0; kc < 4; kc++)
      qf[mi][kc] = *(const short8*)&qkv[(size_t)(b * S_ + qw + mi * 16 + lr) * 3072 +
                                        h * HD_ + kc * 32 + lg * 8];

  auto stageK = [&](int kt) {
#pragma unroll
    for (int c = 0; c < 4; c++) {
      int row = c * 16 + (t >> 4), sl = t & 15;
      gl_lds16(qkv + (size_t)(b * S_ + kt * 64 + row) * 3072 + 2048 + kvh * HD_ +
                   ((sl ^ (row & 15)) << 3),
               &lK[c * 2048 + w * 512]);
    }
  };
  auto stageV = [&](int kt) {
#pragma unroll
    for (int c = 0; c < 4; c++) {
      int row = c * 32 + (t >> 3), sl = t & 7;
      gl_lds16(vt + (size_t)((b * 4 + kvh) * 128 + row) * S_ + kt * 64 +
                   ((sl ^ (row & 7)) << 3),
               &lV[c * 2048 + w * 512]);
    }
  };
  auto computeS = [&](int kt, f32x4 (&s)[2][4]) {
#pragma unroll
    for (int mi = 0; mi < 2; mi++)
#pragma unroll
      for (int ni = 0; ni < 4; ni++) s[mi][ni] = (f32x4){0.f, 0.f, 0.f, 0.f};
#pragma unroll
    for (int kc = 0; kc < 4; kc++) {
      short8 kf[4];
#pragma unroll
      for (int ni = 0; ni < 4; ni++) {
        int row = ni * 16 + lr;
        kf[ni] = *(const short8*)((const char*)lK + row * 256 + (((kc * 4 + lg) ^ (row & 15)) << 4));
      }
#pragma unroll
      for (int mi = 0; mi < 2; mi++)
#pragma unroll
        for (int ni = 0; ni < 4; ni++)
          s[mi][ni] = __builtin_amdgcn_mfma_f32_16x16x32_bf16(qf[mi][kc], kf[ni], s[mi][ni], 0, 0, 0);
    }
    if (kt >= nkt - 2) {   // diagonal tiles: causal mask
#pragma unroll
      for (int mi = 0; mi < 2; mi++)
#pragma unroll
        for (int ni = 0; ni < 4; ni++)
#pragma unroll
          for (int r = 0; r < 4; r++) {
            int colg = kt * 64 + ni * 16 + lr;
            int rowg = qw + mi * 16 + lg * 4 + r;
            s[mi][ni][r] = (colg > rowg) ? -__builtin_inff() : s[mi][ni][r] * SCALE_;
          }
    } else {
#pragma unroll
      for (int mi = 0; mi < 2; mi++)
#pragma unroll
        for (int ni = 0; ni < 4; ni++)
#pragma unroll
          for (int r = 0; r < 4; r++) s[mi][ni][r] *= SCALE_;
    }
  };

  float m_run[2][4], l_run[2][4];
#pragma unroll
  for (int mi = 0; mi < 2; mi++)
#pragma unroll
    for (int r = 0; r < 4; r++) { m_run[mi][r] = -__builtin_inff(); l_run[mi][r] = 0.f; }

  // ---- pass 1: row max + sum ----
  for (int kt = 0; kt < nkt; kt++) {
    stageK(kt);
    __syncthreads();
    f32x4 s[2][4];
    computeS(kt, s);
#pragma unroll
    for (int mi = 0; mi < 2; mi++)
#pragma unroll
      for (int r = 0; r < 4; r++) {
        float mt = fmaxf(fmaxf(s[mi][0][r], s[mi][1][r]), fmaxf(s[mi][2][r], s[mi][3][r]));
#pragma unroll
        for (int off = 1; off < 16; off <<= 1) mt = fmaxf(mt, __shfl_xor(mt, off));
        float mnew = fmaxf(m_run[mi][r], mt);
        float sum = __expf(s[mi][0][r] - mnew) + __expf(s[mi][1][r] - mnew) +
                    __expf(s[mi][2][r] - mnew) + __expf(s[mi][3][r] - mnew);
#pragma unroll
        for (int off = 1; off < 16; off <<= 1) sum += __shfl_xor(sum, off);
        l_run[mi][r] = l_run[mi][r] * __expf(m_run[mi][r] - mnew) + sum;
        m_run[mi][r] = mnew;
      }
    __syncthreads();
  }
  float inv_l[2][4];
#pragma unroll
  for (int mi = 0; mi < 2; mi++)
#pragma unroll
    for (int r = 0; r < 4; r++) inv_l[mi][r] = 1.f / l_run[mi][r];

  // ---- pass 2: exact P (write fp32 + LDS bf16), PV ----
  f32x4 o[2][8];
#pragma unroll
  for (int mi = 0; mi < 2; mi++)
#pragma unroll
    for (int dj = 0; dj < 8; dj++) o[mi][dj] = (f32x4){0.f, 0.f, 0.f, 0.f};
  ushort_t* lPw = lP[w];
  for (int kt = 0; kt < nkt; kt++) {
    stageK(kt);
    stageV(kt);
    __syncthreads();
    f32x4 s[2][4];
    computeS(kt, s);
#pragma unroll
    for (int mi = 0; mi < 2; mi++)
#pragma unroll
      for (int ni = 0; ni < 4; ni++)
#pragma unroll
        for (int r = 0; r < 4; r++) {
          float p = __expf(s[mi][ni][r] - m_run[mi][r]) * inv_l[mi][r];
          int rowl = mi * 16 + lg * 4 + r;   // 0..31
          int col = ni * 16 + lr;            // 0..63
          wout[((size_t)(b * NH + h) * S_ + (q0 + w * 32 + rowl)) * S_ + kt * 64 + col] = p;
          lPw[rowl * 64 + (((col >> 3) ^ (rowl & 7)) << 3) + (col & 7)] = f2bf(p);
        }
#pragma unroll
    for (int kc = 0; kc < 2; kc++) {
      short8 pa[2];
#pragma unroll
      for (int mi = 0; mi < 2; mi++) {
        int row = mi * 16 + lr;
        pa[mi] = *(const short8*)((const char*)lPw + row * 128 + (((kc * 4 + lg) ^ (row & 7)) << 4));
      }
#pragma unroll
      for (int dj = 0; dj < 8; dj++) {
        int row = dj * 16 + lr;
        short8 vb = *(const short8*)((const char*)lV + row * 128 + (((kc * 4 + lg) ^ (row & 7)) << 4));
        o[0][dj] = __builtin_amdgcn_mfma_f32_16x16x32_bf16(pa[0], vb, o[0][dj], 0, 0, 0);
        o[1][dj] = __builtin_amdgcn_mfma_f32_16x16x32_bf16(pa[1], vb, o[1][dj], 0, 0, 0);
      }
    }
    __syncthreads();
  }
  // O -> attn buffer (bf16), [b*S+s][h*128+d]
#pragma unroll
  for (int mi = 0; mi < 2; mi++)
#pragma unroll
    for (int dj = 0; dj < 8; dj++)
#pragma unroll
      for (int r = 0; r < 4; r++) {
        int rowg = b * S_ + qw + mi * 16 + lg * 4 + r;
        int colg = h * HD_ + dj * 16 + lr;
        attnO[(size_t)rowg * Dm + colg] = f2bf(o[mi][dj][r]);
      }
  // zero-fill upper triangle of attn_weights for this q-tile
  int zc0 = nkt * 64;
  int zn4 = (S_ - zc0) >> 2;
  if (zn4 > 0) {
    float4 z4 = {0.f, 0.f, 0.f, 0.f};
    size_t base = (size_t)(b * NH + h) * S_ * S_;
    for (int i = t; i < 128 * zn4; i += 256) {
      int rr = i / zn4, cc = i - rr * zn4;
      *(float4*)&wout[base + (size_t)(q0 + rr) * S_ + zc0 + cc * 4] = z4;
    }
  }
}

// ---------------- host ----------------
extern "C" void kernel_launch(void* const* d_in, const int* in_sizes, int n_in,
                              void* d_out, int out_size, void* d_ws, size_t ws_size,
                              hipStream_t stream) {
  const float* hs   = (const float*)d_in[0];
  const float* cosT = (const float*)d_in[1];
  const float* sinT = (const float*)d_in[2];
  // d_in[3] attention_mask: pure causal, applied analytically
  const float* Wq = (const float*)d_in[4];
  const float* bq = (const float*)d_in[5];
  const float* Wk = (const float*)d_in[6];
  const float* bk = (const float*)d_in[7];
  const float* Wv = (const float*)d_in[8];
  const float* bv = (const float*)d_in[9];
  const float* Wo = (const float*)d_in[10];

  char* ws = (char*)d_ws;
  ushort_t* hsb   = (ushort_t*)(ws);               // 16,777,216 B  [4096][2048] bf16
  ushort_t* wtqkv = (ushort_t*)(ws + 16777216);    // 12,582,912 B  [3072][2048] bf16 (Wq|Wk|Wv)^T
  ushort_t* wto   = (ushort_t*)(ws + 29360128);    //  8,388,608 B  [2048][2048] bf16 Wo^T
  ushort_t* qkv   = (ushort_t*)(ws + 37748736);    // 25,165,824 B  [4096][3072] bf16
  ushort_t* vt    = (ushort_t*)(ws + 62914560);    //  4,194,304 B  [8][128][2048] bf16
  ushort_t* attn  = (ushort_t*)(ws);               // reuse hsb region (dead after gemm_qkv)

  float* outO = (float*)d_out;            // [2,2048,2048] attn_out
  float* outW = outO + (size_t)8388608;   // [2,16,2048,2048] attn_weights

  conv_f32_bf16<<<8192, 256, 0, stream>>>(hs, hsb);
  transpose_conv<<<dim3(64, 64), 256, 0, stream>>>(Wq, 2048, wtqkv);
  transpose_conv<<<dim3(16, 64), 256, 0, stream>>>(Wk, 512, wtqkv + (size_t)2048 * 2048);
  transpose_conv<<<dim3(16, 64), 256, 0, stream>>>(Wv, 512, wtqkv + (size_t)2560 * 2048);
  transpose_conv<<<dim3(64, 64), 256, 0, stream>>>(Wo, 2048, wto);
  gemm_bt_k<0><<<dim3(24, 32), 256, 0, stream>>>(hsb, wtqkv, qkv, 3072, 2048, bq, bk, bv);
  rope_k<<<20480, 256, 0, stream>>>(qkv, cosT, sinT);
  transpose_v<<<dim3(64, 4, 8), 256, 0, stream>>>(qkv, vt);
  attn_k<<<dim3(16, 16, 2), 256, 0, stream>>>(qkv, vt, outW, attn);
  gemm_bt_k<1><<<dim3(16, 32), 256, 0, stream>>>(attn, wto, outO, 2048, 2048, nullptr, nullptr,
                                                 nullptr);
}

// Round 2
// 427.943 us; speedup vs baseline: 1.0587x; 1.0587x over previous
//
#include <hip/hip_runtime.h>

typedef unsigned short ushort_t;
typedef __attribute__((ext_vector_type(8))) short short8;   // 8 bf16 (4 VGPRs)
typedef __attribute__((ext_vector_type(4))) float f32x4;

#define S_  2048
#define Dm  2048
#define NH  16
#define NKV 4
#define HD_ 128
#define SCALE_ 0.08838834764831845f

__device__ __forceinline__ ushort_t f2bf(float f) {
  union { float f; unsigned u; } v; v.f = f;
  unsigned u = v.u;
  return (ushort_t)((u + 0x7FFFu + ((u >> 16) & 1u)) >> 16);   // RNE
}
__device__ __forceinline__ float bf2f(ushort_t h) {
  union { unsigned u; float f; } v; v.u = ((unsigned)h) << 16;
  return v.f;
}
__device__ __forceinline__ void gl_lds16(const void* g, void* l) {
  __builtin_amdgcn_global_load_lds((const __attribute__((address_space(1))) void*)g,
                                   (__attribute__((address_space(3))) void*)l, 16, 0, 0);
}

// ---------------- converters ----------------
__global__ void conv_f32_bf16(const float* __restrict__ src, ushort_t* __restrict__ dst) {
  int i = blockIdx.x * 256 + threadIdx.x;          // exact grid, no bounds check
  float4 v = ((const float4*)src)[i];
  union { ushort_t u[4]; uint2 v2; } o;
  o.u[0] = f2bf(v.x); o.u[1] = f2bf(v.y); o.u[2] = f2bf(v.z); o.u[3] = f2bf(v.w);
  *(uint2*)&dst[(size_t)i * 4] = o.v2;
}

// dst[n][k] = src[k][n], dst leading dim 2048, src is [2048][N] fp32
__global__ void transpose_conv(const float* __restrict__ src, int N, ushort_t* __restrict__ dst) {
  __shared__ float tile[32][33];
  int n0 = blockIdx.x * 32, k0 = blockIdx.y * 32;
  int c = threadIdx.x & 31, r = threadIdx.x >> 5;   // r: 0..7
#pragma unroll
  for (int i = 0; i < 32; i += 8)
    tile[r + i][c] = src[(size_t)(k0 + r + i) * N + n0 + c];
  __syncthreads();
#pragma unroll
  for (int i = 0; i < 32; i += 8)
    dst[(size_t)(n0 + r + i) * 2048 + k0 + c] = f2bf(tile[c][r + i]);
}

// vt[(b*4+kvh)*128 + d][s] = V[b*2048+s][d]  (V = qkv cols 2560..3071)
__global__ void transpose_v(const ushort_t* __restrict__ qkv, ushort_t* __restrict__ vt) {
  __shared__ ushort_t tile[32][33];
  int b = blockIdx.z >> 2, kvh = blockIdx.z & 3;
  int s0 = blockIdx.x * 32, d0 = blockIdx.y * 32;
  int c = threadIdx.x & 31, r = threadIdx.x >> 5;
#pragma unroll
  for (int i = 0; i < 32; i += 8)
    tile[r + i][c] = qkv[(size_t)(b * S_ + s0 + r + i) * 3072 + 2560 + kvh * HD_ + d0 + c];
  __syncthreads();
#pragma unroll
  for (int i = 0; i < 32; i += 8)
    vt[(size_t)(blockIdx.z * 128 + d0 + r + i) * S_ + s0 + c] = tile[c][r + i];
}

// ---------------- RoPE in place on Q,K ----------------
__global__ void rope_k(ushort_t* __restrict__ qkv, const float* __restrict__ cosT,
                       const float* __restrict__ sinT) {
  int idx = blockIdx.x * 256 + threadIdx.x;   // 4096*20*64 exact
  int d = idx & 63;
  int rest = idx >> 6;
  int hh = rest % 20;
  int row = rest / 20;
  int b = row >> 11, s = row & 2047;
  int col0 = (hh < 16) ? hh * 128 : 2048 + (hh - 16) * 128;
  float c  = cosT[(size_t)(b * S_ + s) * HD_ + d];   // cos[d] == cos[d+64]
  float sn = sinT[(size_t)(b * S_ + s) * HD_ + d];
  ushort_t* p = qkv + (size_t)row * 3072 + col0 + d;
  float v0 = bf2f(p[0]), v1 = bf2f(p[64]);
  p[0]  = f2bf(v0 * c - v1 * sn);
  p[64] = f2bf(v1 * c + v0 * sn);
}

// ---------------- GEMM: C[M][N] = A[M][K] @ Bt[N][K]^T, bf16 in, m97 structure ----------------
// MODE 0: bf16 out + packed qkv bias.  MODE 1: fp32 out, no bias.
template <int MODE>
__global__ __launch_bounds__(256, 2) void gemm_bt_k(
    const ushort_t* __restrict__ A, const ushort_t* __restrict__ Bt, void* __restrict__ C,
    int N, int K, const float* __restrict__ bq, const float* __restrict__ bk2,
    const float* __restrict__ bv) {
  __shared__ ushort_t lA[128 * 32];   // 8KB, source-pre-swizzled: slot ^= (row>>1)&3
  __shared__ ushort_t lB[128 * 32];
  const int n0 = blockIdx.x * 128, m0 = blockIdx.y * 128;
  const int t = threadIdx.x;
  const int w = t >> 6, l = t & 63, lr = l & 15, lg = l >> 4;
  const int wr = w >> 1, wc = w & 1;
  const int srow = t >> 2, ssl = t & 3;

  f32x4 acc[4][4];
#pragma unroll
  for (int i = 0; i < 4; i++)
#pragma unroll
    for (int j = 0; j < 4; j++) acc[i][j] = (f32x4){0.f, 0.f, 0.f, 0.f};

  for (int kt = 0; kt < K; kt += 32) {
    {
      int r0 = srow, r1 = srow + 64;
      gl_lds16(A + (size_t)(m0 + r0) * K + kt + ((ssl ^ ((r0 >> 1) & 3)) << 3), &lA[w * 512]);
      gl_lds16(A + (size_t)(m0 + r1) * K + kt + ((ssl ^ ((r1 >> 1) & 3)) << 3), &lA[2048 + w * 512]);
      gl_lds16(Bt + (size_t)(n0 + r0) * K + kt + ((ssl ^ ((r0 >> 1) & 3)) << 3), &lB[w * 512]);
      gl_lds16(Bt + (size_t)(n0 + r1) * K + kt + ((ssl ^ ((r1 >> 1) & 3)) << 3), &lB[2048 + w * 512]);
    }
    __syncthreads();
    short8 af[4], bfr[4];
#pragma unroll
    for (int mi = 0; mi < 4; mi++) {
      int row = wr * 64 + mi * 16 + lr;
      af[mi] = *(const short8*)((const char*)lA + row * 64 + ((lg ^ ((row >> 1) & 3)) << 4));
    }
#pragma unroll
    for (int ni = 0; ni < 4; ni++) {
      int row = wc * 64 + ni * 16 + lr;
      bfr[ni] = *(const short8*)((const char*)lB + row * 64 + ((lg ^ ((row >> 1) & 3)) << 4));
    }
#pragma unroll
    for (int mi = 0; mi < 4; mi++)
#pragma unroll
      for (int ni = 0; ni < 4; ni++)
        acc[mi][ni] = __builtin_amdgcn_mfma_f32_16x16x32_bf16(af[mi], bfr[ni], acc[mi][ni], 0, 0, 0);
    __syncthreads();
  }
#pragma unroll
  for (int mi = 0; mi < 4; mi++)
#pragma unroll
    for (int ni = 0; ni < 4; ni++)
#pragma unroll
      for (int r = 0; r < 4; r++) {
        int row = m0 + wr * 64 + mi * 16 + lg * 4 + r;   // C/D: col=lane&15, row=(lane>>4)*4+reg
        int col = n0 + wc * 64 + ni * 16 + lr;
        float v = acc[mi][ni][r];
        if (MODE == 0) {
          float bias = (col < 2048) ? bq[col] : (col < 2560) ? bk2[col - 2048] : bv[col - 2560];
          ((ushort_t*)C)[(size_t)row * N + col] = f2bf(v + bias);
        } else {
          ((float*)C)[(size_t)row * N + col] = v;
        }
      }
}

// ---------------- fused causal GQA attention, SINGLE pass (m=0), unnormalized P~ ----------------
// Each block handles q-tiles {pairI, 15-pairI}: constant 34 k-tiles of work per block.
__global__ __launch_bounds__(256, 2) void attn_k(
    const ushort_t* __restrict__ qkv, const ushort_t* __restrict__ vt,
    ushort_t* __restrict__ pw, float* __restrict__ linv_g, ushort_t* __restrict__ attnO) {
  __shared__ ushort_t lK[64 * 128];     // [k][d], 16 slots/row, slot ^= row&15
  __shared__ ushort_t lV[128 * 64];     // [d][k], 8 slots/row,  slot ^= row&7
  __shared__ ushort_t lP[4][32 * 64];   // per-wave P~, 8 slots/row, slot ^= row&7
  const int pairI = blockIdx.x, h = blockIdx.y, b = blockIdx.z;
  const int kvh = h >> 2;
  const int t = threadIdx.x, w = t >> 6, l = t & 63, lr = l & 15, lg = l >> 4;
  ushort_t* lPw = lP[w];

  for (int sel = 0; sel < 2; sel++) {
    const int qt = sel ? (15 - pairI) : pairI;
    const int q0 = qt * 128;
    const int qw = q0 + w * 32;
    const int nkt = (qt + 1) * 2;

    // Q fragments in registers (A-frag: row=lane&15, k=(lane>>4)*8+i)
    short8 qf[2][4];
#pragma unroll
    for (int mi = 0; mi < 2; mi++)
#pragma unroll
      for (int kc = 0; kc < 4; kc++)
        qf[mi][kc] = *(const short8*)&qkv[(size_t)(b * S_ + qw + mi * 16 + lr) * 3072 +
                                          h * HD_ + kc * 32 + lg * 8];

    float lsum[2][4];
    f32x4 o[2][8];
#pragma unroll
    for (int mi = 0; mi < 2; mi++) {
#pragma unroll
      for (int r = 0; r < 4; r++) lsum[mi][r] = 0.f;
#pragma unroll
      for (int dj = 0; dj < 8; dj++) o[mi][dj] = (f32x4){0.f, 0.f, 0.f, 0.f};
    }

    for (int kt = 0; kt < nkt; kt++) {
      // stage K tile [64][128] and V tile [128][64]
#pragma unroll
      for (int c = 0; c < 4; c++) {
        int row = c * 16 + (t >> 4), sl = t & 15;
        gl_lds16(qkv + (size_t)(b * S_ + kt * 64 + row) * 3072 + 2048 + kvh * HD_ +
                     ((sl ^ (row & 15)) << 3),
                 &lK[c * 2048 + w * 512]);
      }
#pragma unroll
      for (int c = 0; c < 4; c++) {
        int row = c * 32 + (t >> 3), sl = t & 7;
        gl_lds16(vt + (size_t)((b * 4 + kvh) * 128 + row) * S_ + kt * 64 +
                     ((sl ^ (row & 7)) << 3),
                 &lV[c * 2048 + w * 512]);
      }
      __syncthreads();

      // S = Q K^T
      f32x4 s[2][4];
#pragma unroll
      for (int mi = 0; mi < 2; mi++)
#pragma unroll
        for (int ni = 0; ni < 4; ni++) s[mi][ni] = (f32x4){0.f, 0.f, 0.f, 0.f};
#pragma unroll
      for (int kc = 0; kc < 4; kc++) {
        short8 kf[4];
#pragma unroll
        for (int ni = 0; ni < 4; ni++) {
          int row = ni * 16 + lr;
          kf[ni] =
              *(const short8*)((const char*)lK + row * 256 + (((kc * 4 + lg) ^ (row & 15)) << 4));
        }
#pragma unroll
        for (int mi = 0; mi < 2; mi++)
#pragma unroll
          for (int ni = 0; ni < 4; ni++)
            s[mi][ni] =
                __builtin_amdgcn_mfma_f32_16x16x32_bf16(qf[mi][kc], kf[ni], s[mi][ni], 0, 0, 0);
      }

      // P~ = exp(S*scale) (m=0; scores bounded), causal zero on diagonal tiles
      const bool diag = (kt >= nkt - 2);
#pragma unroll
      for (int mi = 0; mi < 2; mi++)
#pragma unroll
        for (int ni = 0; ni < 4; ni++)
#pragma unroll
          for (int r = 0; r < 4; r++) {
            float p = __expf(s[mi][ni][r] * SCALE_);
            if (diag) {
              int colg = kt * 64 + ni * 16 + lr;
              int rowg = qw + mi * 16 + lg * 4 + r;
              if (colg > rowg) p = 0.f;
            }
            lsum[mi][r] += p;
            int rowl = mi * 16 + lg * 4 + r;   // 0..31
            int col = ni * 16 + lr;            // 0..63
            lPw[rowl * 64 + (((col >> 3) ^ (rowl & 7)) << 3) + (col & 7)] = f2bf(p);
          }

      // copy this wave's P~ tile to global scratch (coalesced 128B row segments)
      {
        int prow = l >> 1;
        int sl0 = (l & 1) * 4;
        size_t gbase = ((size_t)(b * NH + h) * S_ + qw + prow) * S_ + kt * 64;
#pragma unroll
        for (int s4 = 0; s4 < 4; s4++) {
          int sIdx = sl0 + s4;
          short8 vv =
              *(const short8*)((const char*)lPw + prow * 128 + ((sIdx ^ (prow & 7)) << 4));
          *(short8*)&pw[gbase + sIdx * 8] = vv;
        }
      }

      // O += P~ V
#pragma unroll
      for (int kc = 0; kc < 2; kc++) {
        short8 pa[2];
#pragma unroll
        for (int mi = 0; mi < 2; mi++) {
          int row = mi * 16 + lr;
          pa[mi] =
              *(const short8*)((const char*)lPw + row * 128 + (((kc * 4 + lg) ^ (row & 7)) << 4));
        }
#pragma unroll
        for (int dj = 0; dj < 8; dj++) {
          int row = dj * 16 + lr;
          short8 vb =
              *(const short8*)((const char*)lV + row * 128 + (((kc * 4 + lg) ^ (row & 7)) << 4));
          o[0][dj] = __builtin_amdgcn_mfma_f32_16x16x32_bf16(pa[0], vb, o[0][dj], 0, 0, 0);
          o[1][dj] = __builtin_amdgcn_mfma_f32_16x16x32_bf16(pa[1], vb, o[1][dj], 0, 0, 0);
        }
      }
      __syncthreads();
    }

    // row-sum reduce over the 16 lr lanes, write inv_l + normalized O
    float inv_l[2][4];
#pragma unroll
    for (int mi = 0; mi < 2; mi++)
#pragma unroll
      for (int r = 0; r < 4; r++) {
        float sum = lsum[mi][r];
#pragma unroll
        for (int off = 1; off < 16; off <<= 1) sum += __shfl_xor(sum, off);
        inv_l[mi][r] = 1.f / sum;
        if (lr == 0)
          linv_g[(size_t)(b * NH + h) * S_ + qw + mi * 16 + lg * 4 + r] = inv_l[mi][r];
      }
#pragma unroll
    for (int mi = 0; mi < 2; mi++)
#pragma unroll
      for (int dj = 0; dj < 8; dj++)
#pragma unroll
        for (int r = 0; r < 4; r++) {
          int rowg = b * S_ + qw + mi * 16 + lg * 4 + r;
          int colg = h * HD_ + dj * 16 + lr;
          attnO[(size_t)rowg * Dm + colg] = f2bf(o[mi][dj][r] * inv_l[mi][r]);
        }
  }
}

// ---------------- normalize + expand: outW[row][k] = (k<=q) ? bf2f(pw)*inv : 0 ----------------
__global__ void norm_expand(const ushort_t* __restrict__ pw, const float* __restrict__ linv,
                            float* __restrict__ outW) {
  int row = blockIdx.x;            // (b*16+h)*2048 + q, 65536 rows
  int q = row & 2047;
  float inv = linv[row];
  int c0 = threadIdx.x * 8;
  float o[8];
  if (c0 <= q) {
    short8 v = *(const short8*)&pw[(size_t)row * 2048 + c0];
#pragma unroll
    for (int j = 0; j < 8; j++) o[j] = (c0 + j <= q) ? bf2f((ushort_t)v[j]) * inv : 0.f;
  } else {
#pragma unroll
    for (int j = 0; j < 8; j++) o[j] = 0.f;
  }
  float* dst = &outW[(size_t)row * 2048 + c0];
  *(float4*)dst = (float4){o[0], o[1], o[2], o[3]};
  *(float4*)(dst + 4) = (float4){o[4], o[5], o[6], o[7]};
}

// ---------------- host ----------------
extern "C" void kernel_launch(void* const* d_in, const int* in_sizes, int n_in,
                              void* d_out, int out_size, void* d_ws, size_t ws_size,
                              hipStream_t stream) {
  const float* hs   = (const float*)d_in[0];
  const float* cosT = (const float*)d_in[1];
  const float* sinT = (const float*)d_in[2];
  // d_in[3] attention_mask: pure causal, applied analytically
  const float* Wq = (const float*)d_in[4];
  const float* bq = (const float*)d_in[5];
  const float* Wk = (const float*)d_in[6];
  const float* bk = (const float*)d_in[7];
  const float* Wv = (const float*)d_in[8];
  const float* bv = (const float*)d_in[9];
  const float* Wo = (const float*)d_in[10];

  char* ws = (char*)d_ws;
  ushort_t* hsb   = (ushort_t*)(ws);               // 16,777,216 B  [4096][2048] bf16
  ushort_t* wtqkv = (ushort_t*)(ws + 16777216);    // 12,582,912 B  [3072][2048] bf16 (Wq|Wk|Wv)^T
  ushort_t* wto   = (ushort_t*)(ws + 29360128);    //  8,388,608 B  [2048][2048] bf16 Wo^T
  ushort_t* qkv   = (ushort_t*)(ws + 37748736);    // 25,165,824 B  [4096][3072] bf16
  ushort_t* vt    = (ushort_t*)(ws + 62914560);    //  4,194,304 B  [8][128][2048] bf16
  ushort_t* pw    = (ushort_t*)(ws + 67108864);    // 268,435,456 B [2][16][2048][2048] bf16 P~
  float*    linv  = (float*)(ws + 335544320);      //     262,144 B [2][16][2048] f32
  ushort_t* attn  = (ushort_t*)(ws);               // reuse hsb region (dead after gemm_qkv)

  float* outO = (float*)d_out;            // [2,2048,2048] attn_out
  float* outW = outO + (size_t)8388608;   // [2,16,2048,2048] attn_weights

  conv_f32_bf16<<<8192, 256, 0, stream>>>(hs, hsb);
  transpose_conv<<<dim3(64, 64), 256, 0, stream>>>(Wq, 2048, wtqkv);
  transpose_conv<<<dim3(16, 64), 256, 0, stream>>>(Wk, 512, wtqkv + (size_t)2048 * 2048);
  transpose_conv<<<dim3(16, 64), 256, 0, stream>>>(Wv, 512, wtqkv + (size_t)2560 * 2048);
  transpose_conv<<<dim3(64, 64), 256, 0, stream>>>(Wo, 2048, wto);
  gemm_bt_k<0><<<dim3(24, 32), 256, 0, stream>>>(hsb, wtqkv, qkv, 3072, 2048, bq, bk, bv);
  rope_k<<<20480, 256, 0, stream>>>(qkv, cosT, sinT);
  transpose_v<<<dim3(64, 4, 8), 256, 0, stream>>>(qkv, vt);
  attn_k<<<dim3(8, 16, 2), 256, 0, stream>>>(qkv, vt, pw, linv, attn);
  norm_expand<<<65536, 256, 0, stream>>>(pw, linv, outW);
  gemm_bt_k<1><<<dim3(16, 32), 256, 0, stream>>>(attn, wto, outO, 2048, 2048, nullptr, nullptr,
                                                 nullptr);
}